// Round 1
// 350.152 us; speedup vs baseline: 1.0179x; 1.0179x over previous
//
#include <hip/hip_runtime.h>
#include <cstdint>
#include <cstddef>

// ---------- bf16 helpers (bit-level) ----------
__device__ __forceinline__ float bf2f(uint16_t u) {
    union { uint32_t i; float f; } w; w.i = ((uint32_t)u) << 16; return w.f;
}
__device__ __forceinline__ uint16_t f2bf(float f) {
    union { float f; uint32_t i; } w; w.f = f;
    uint32_t x = w.i;
    uint32_t r = (x + 0x7FFFu + ((x >> 16) & 1u)) >> 16;   // RNE
    return (uint16_t)r;
}

typedef __bf16 bf16x8 __attribute__((ext_vector_type(8)));
typedef float  f32x4  __attribute__((ext_vector_type(4)));

// async global->LDS, 16B per lane; LDS dest is wave-uniform base + lane*16
__device__ __forceinline__ void load_lds16(const void* gptr, void* lptr) {
    __builtin_amdgcn_global_load_lds(
        (__attribute__((address_space(1))) void*)gptr,
        (__attribute__((address_space(3))) void*)lptr,
        16, 0, 0);
}

// ---------- generic GEMM (128x128, legacy engine): C = act(A @ BT^T + bias) ----------
// Kept for GEMM1 (fp32 A staging) and the batched output GEMM.
template<int AFP32, int OUTFP32, int RELU>
__global__ __launch_bounds__(256, 3)
void gemm_bt(const void* __restrict__ Av, const uint16_t* __restrict__ BT,
             const float* __restrict__ bias, void* __restrict__ Cv,
             int K, int lda, int ldb, int ldc,
             long long sA, long long sB, long long sC)
{
    __shared__ uint16_t As[128 * 32];
    __shared__ uint16_t Bs[128 * 32];

    const int nx = (int)gridDim.x, ny = (int)gridDim.y, nz = (int)gridDim.z;
    const int g   = (int)blockIdx.x + nx * ((int)blockIdx.y + ny * (int)blockIdx.z);
    const int xcd = g & 7;
    const int ii  = g >> 3;
    const int xz  = 8 / nz;
    const int bz  = xcd / xz;
    const int sub = xcd % xz;
    const int ypc = ny / xz;
    const int by  = sub * ypc + ii % ypc;
    const int bx  = ii / ypc;

    const int t    = threadIdx.x;
    const int lane = t & 63;
    const int w    = t >> 6;
    const int quad = lane >> 4;
    const int l15  = lane & 15;
    const int wr   = w >> 1;
    const int wc   = w & 1;
    const int gm0  = by * 128;
    const int gn0  = bx * 128;

    BT += (long long)bz * sB;

    f32x4 acc[4][4] = {};

    const int ch_r = lane >> 2;
    const int ch_c = (lane & 3) * 8;

    for (int k0 = 0; k0 < K; k0 += 32) {
        __syncthreads();
        {
            int row = w * 16 + ch_r;
            load_lds16(BT + (size_t)(gn0 + row) * ldb + k0 + ch_c, (void*)(Bs + w * 512));
            load_lds16(BT + (size_t)(gn0 + row + 64) * ldb + k0 + ch_c, (void*)(Bs + (w + 4) * 512));
        }
        if (AFP32) {
            const float* A = (const float*)Av + (long long)bz * sA;
            const int row = t >> 1, half = t & 1;
            const float* ap = A + (size_t)(gm0 + row) * lda + k0 + half * 16;
            float4 f0 = ((const float4*)ap)[0];
            float4 f1 = ((const float4*)ap)[1];
            float4 f2 = ((const float4*)ap)[2];
            float4 f3 = ((const float4*)ap)[3];
            union { __bf16 h[16]; uint4 q[2]; } u;
            u.h[0]  = (__bf16)f0.x; u.h[1]  = (__bf16)f0.y;
            u.h[2]  = (__bf16)f0.z; u.h[3]  = (__bf16)f0.w;
            u.h[4]  = (__bf16)f1.x; u.h[5]  = (__bf16)f1.y;
            u.h[6]  = (__bf16)f1.z; u.h[7]  = (__bf16)f1.w;
            u.h[8]  = (__bf16)f2.x; u.h[9]  = (__bf16)f2.y;
            u.h[10] = (__bf16)f2.z; u.h[11] = (__bf16)f2.w;
            u.h[12] = (__bf16)f3.x; u.h[13] = (__bf16)f3.y;
            u.h[14] = (__bf16)f3.z; u.h[15] = (__bf16)f3.w;
            uint4* d = (uint4*)(As + row * 32 + half * 16);
            d[0] = u.q[0];
            d[1] = u.q[1];
        } else {
            const uint16_t* A = (const uint16_t*)Av + (long long)bz * sA;
            int row = w * 16 + ch_r;
            load_lds16(A + (size_t)(gm0 + row) * lda + k0 + ch_c, (void*)(As + w * 512));
            load_lds16(A + (size_t)(gm0 + row + 64) * lda + k0 + ch_c, (void*)(As + (w + 4) * 512));
        }
        __syncthreads();

        bf16x8 af[4], bfr[4];
#pragma unroll
        for (int i = 0; i < 4; i++) {
            af[i]  = *(const bf16x8*)(As + (wr * 64 + i * 16 + l15) * 32 + quad * 8);
            bfr[i] = *(const bf16x8*)(Bs + (wc * 64 + i * 16 + l15) * 32 + quad * 8);
        }
#pragma unroll
        for (int mi = 0; mi < 4; mi++)
#pragma unroll
            for (int ni = 0; ni < 4; ni++)
                acc[mi][ni] = __builtin_amdgcn_mfma_f32_16x16x32_bf16(af[mi], bfr[ni], acc[mi][ni], 0, 0, 0);
    }

#pragma unroll
    for (int ni = 0; ni < 4; ni++) {
        const int gcol = gn0 + wc * 64 + ni * 16 + l15;
        const float bv = bias ? bias[gcol] : 0.0f;
#pragma unroll
        for (int mi = 0; mi < 4; mi++) {
#pragma unroll
            for (int r = 0; r < 4; r++) {
                const int grow = gm0 + wr * 64 + mi * 16 + quad * 4 + r;
                float v = acc[mi][ni][r] + bv;
                if (RELU) v = fmaxf(v, 0.0f);
                if (OUTFP32) {
                    float* C = (float*)Cv + (long long)bz * sC;
                    C[(size_t)grow * ldc + gcol] = v;
                } else {
                    uint16_t* C = (uint16_t*)Cv + (long long)bz * sC;
                    C[(size_t)grow * ldc + gcol] = f2bf(v);
                }
            }
        }
    }
}

// ---------- 256x256 8-phase GEMM (T2+T3+T4+T5, plain HIP) ----------
// C[M,N] = act(A[M,K] @ BT[N,K]^T + bias); A,BT bf16; BK=64 split in 2 k-halves.
// 8 waves (512 thr): wave (wr=w>>2, wc=w&3) owns rows wr*128..+127, cols wc*64..+63.
// LDS 128 KiB dynamic:  A[buf][kh] subtiles [256][32] at (buf*2+kh)*8192 elems,
//                       B same at +32768.  16B chunk swizzle within each row:
//   LDS slot (r,q) holds global chunk (q ^ ((r>>1)&3)) of row r.
//   -> ds_read_b128 frag reads land 2 lanes/bank-group (free, T2); gload_lds dest
//      stays linear, source address carries the inverse (= same) XOR.
// Per K-tile: 4 phases (kh,mh): [ds_read 8|4 frags][stage 1 half: 2 gload_lds]
//   [s_barrier][setprio(1) 16 MFMA setprio(0)][vmcnt(4) @ ph1,ph3][s_barrier]
// vmcnt(4) at end ph1 -> current tile's (Ak1,Bk1) landed for ph2;
// vmcnt(4) at end ph3 -> next tile's (Ak0,Bk0) landed for its ph0.
// 4-8 loads stay in flight; the loop never drains vmcnt to 0 (T4).
template<int OUTFP32, int RELU>
__global__ __launch_bounds__(512, 2)
void gemm256_bt(const uint16_t* __restrict__ A, const uint16_t* __restrict__ BT,
                const float* __restrict__ bias, void* __restrict__ Cv,
                int K, int lda, int ldb, int ldc)
{
    extern __shared__ uint16_t lds[];   // 65536 elems = 128 KiB

    // XCD swizzle, grid (8,32)=256 blocks, 1 block/CU: each XCD owns a 4-tile M band.
    const int g   = (int)blockIdx.x + 8 * (int)blockIdx.y;
    const int xcd = g & 7, ii = g >> 3;
    const int by  = xcd * 4 + (ii & 3);
    const int bx  = ii >> 2;
    const int gm0 = by * 256, gn0 = bx * 256;

    const int t    = threadIdx.x;
    const int w    = t >> 6, lane = t & 63;
    const int l15  = lane & 15, quad = lane >> 4;
    const int wr   = w >> 2, wc = w & 3;

    // frag-read swizzle + row bases
    const int cpr  = quad ^ ((l15 >> 1) & 3);
    const int arow = wr * 128 + l15;                 // + mh*64 + i*16
    const int brow = wc * 64 + l15;                  // + ni*16

    // staging map: thread t, inst j in {0,1}: chunk c=j*512+t of a 16KB k-half;
    // row r = c>>2 (j=1 -> +128), global chunk qg = (c&3) ^ ((r>>1)&3); base-indep
    // because halves are 16-row aligned -> qg identical for both insts.
    const int r0 = t >> 2;
    const int qg = (t & 3) ^ ((t >> 3) & 3);
    const uint16_t* aS0 = A  + (size_t)(gm0 + r0) * lda + qg * 8;
    const uint16_t* aS1 = aS0 + (size_t)128 * lda;
    const uint16_t* bS0 = BT + (size_t)(gn0 + r0) * ldb + qg * 8;
    const uint16_t* bS1 = bS0 + (size_t)128 * ldb;
    // LDS dst (wave-uniform; HW adds lane*16B)
    const int ldst0 = (w * 64) * 8;
    const int ldst1 = (512 + w * 64) * 8;

#define SUBA(nb, kh) (lds + ((nb) * 2 + (kh)) * 8192)
#define SUBB(nb, kh) (lds + 32768 + ((nb) * 2 + (kh)) * 8192)
#define STAGE_A(nb, kh, k0s) do {                                              \
        load_lds16(aS0 + (k0s) + (kh) * 32, (void*)(SUBA(nb, kh) + ldst0));    \
        load_lds16(aS1 + (k0s) + (kh) * 32, (void*)(SUBA(nb, kh) + ldst1));    \
    } while (0)
#define STAGE_B(nb, kh, k0s) do {                                              \
        load_lds16(bS0 + (k0s) + (kh) * 32, (void*)(SUBB(nb, kh) + ldst0));    \
        load_lds16(bS1 + (k0s) + (kh) * 32, (void*)(SUBB(nb, kh) + ldst1));    \
    } while (0)
#define VMWAIT4 asm volatile("s_waitcnt vmcnt(4)" ::: "memory")
#define NOWAIT  ((void)0)

    f32x4 acc[8][4] = {};
    bf16x8 bF[4];

    // prologue: stage tile 0 fully (issue order Ak0,Bk0,Ak1,Bk1 = 8 insts)
    STAGE_A(0, 0, 0); STAGE_B(0, 0, 0); STAGE_A(0, 1, 0); STAGE_B(0, 1, 0);
    VMWAIT4;                               // Ak0,Bk0 landed (oldest 4)
    __builtin_amdgcn_s_barrier();

    const int NT = K >> 6;
    for (int kt = 0; kt < NT; ++kt) {
        const int buf = kt & 1, nb = buf ^ 1;
        const int nk0 = (kt + 1 < NT) ? ((kt + 1) << 6) : 0;   // wrap: dead stage

#define PHASE(kh, mh, STAGE_STMT, VM_STMT)                                          \
        {                                                                           \
            const uint16_t* As_ = SUBA(buf, kh);                                    \
            const uint16_t* Bs_ = SUBB(buf, kh);                                    \
            bf16x8 aF[4];                                                           \
            _Pragma("unroll")                                                       \
            for (int i = 0; i < 4; i++)                                             \
                aF[i] = *(const bf16x8*)(As_ + (arow + (mh) * 64 + i * 16) * 32 + cpr * 8); \
            if ((mh) == 0) {                                                        \
                _Pragma("unroll")                                                   \
                for (int ni = 0; ni < 4; ni++)                                      \
                    bF[ni] = *(const bf16x8*)(Bs_ + (brow + ni * 16) * 32 + cpr * 8); \
            }                                                                       \
            STAGE_STMT;                                                             \
            __builtin_amdgcn_s_barrier();                                           \
            __builtin_amdgcn_s_setprio(1);                                          \
            _Pragma("unroll")                                                       \
            for (int i = 0; i < 4; i++)                                             \
                _Pragma("unroll")                                                   \
                for (int ni = 0; ni < 4; ni++)                                      \
                    acc[(mh) * 4 + i][ni] = __builtin_amdgcn_mfma_f32_16x16x32_bf16( \
                        aF[i], bF[ni], acc[(mh) * 4 + i][ni], 0, 0, 0);             \
            __builtin_amdgcn_s_setprio(0);                                          \
            VM_STMT;                                                                \
            __builtin_amdgcn_s_barrier();                                           \
        }

        PHASE(0, 0, STAGE_A(nb, 0, nk0), NOWAIT)
        PHASE(0, 1, STAGE_B(nb, 0, nk0), VMWAIT4)
        PHASE(1, 0, STAGE_A(nb, 1, nk0), NOWAIT)
        PHASE(1, 1, STAGE_B(nb, 1, nk0), VMWAIT4)
#undef PHASE
    }
    asm volatile("s_waitcnt vmcnt(0)" ::: "memory");   // drain dead stage

    // epilogue: C/D layout col=lane&15, row=quad*4+reg
#pragma unroll
    for (int ni = 0; ni < 4; ni++) {
        const int gcol = gn0 + wc * 64 + ni * 16 + l15;
        const float bv = bias ? bias[gcol] : 0.0f;
#pragma unroll
        for (int mi = 0; mi < 8; mi++) {
#pragma unroll
            for (int r = 0; r < 4; r++) {
                const int grow = gm0 + wr * 128 + mi * 16 + quad * 4 + r;
                float v = acc[mi][ni][r] + bv;
                if (RELU) v = fmaxf(v, 0.0f);
                if (OUTFP32) ((float*)Cv)[(size_t)grow * ldc + gcol] = v;
                else         ((uint16_t*)Cv)[(size_t)grow * ldc + gcol] = f2bf(v);
            }
        }
    }
#undef SUBA
#undef SUBB
#undef STAGE_A
#undef STAGE_B
#undef VMWAIT4
#undef NOWAIT
}

// ---------- transpose fp32 -> bf16: dst[n][k] = bf16(src[k][n]) ----------
__global__ __launch_bounds__(256)
void transpose_f32_to_bf16(const float* __restrict__ src, uint16_t* __restrict__ dst,
                           int src_ld, int dst_ld)
{
    __shared__ uint16_t tile[64 * 65];
    const int k0 = blockIdx.y * 64, n0 = blockIdx.x * 64;
    const int t = threadIdx.x;
#pragma unroll
    for (int i = 0; i < 16; i++) {
        int idx = i * 256 + t;
        int r = idx >> 6, c = idx & 63;
        tile[c * 65 + r] = f2bf(src[(size_t)(k0 + r) * src_ld + n0 + c]);
    }
    __syncthreads();
#pragma unroll
    for (int i = 0; i < 16; i++) {
        int idx = i * 256 + t;
        int n = idx >> 6, k = idx & 63;
        dst[(size_t)(n0 + n) * dst_ld + k0 + k] = tile[n * 65 + k];
    }
}

// ---------- transpose bf16 -> bf16 (batched) ----------
__global__ __launch_bounds__(256)
void transpose_bf16(const uint16_t* __restrict__ src, uint16_t* __restrict__ dst,
                    int src_ld, int dst_ld, long long sS, long long sD)
{
    __shared__ uint16_t tile[64 * 65];
    src += (long long)blockIdx.z * sS;
    dst += (long long)blockIdx.z * sD;
    const int k0 = blockIdx.y * 64, n0 = blockIdx.x * 64;
    const int t = threadIdx.x;
#pragma unroll
    for (int i = 0; i < 16; i++) {
        int idx = i * 256 + t;
        int r = idx >> 6, c = idx & 63;
        tile[c * 65 + r] = src[(size_t)(k0 + r) * src_ld + n0 + c];
    }
    __syncthreads();
#pragma unroll
    for (int i = 0; i < 16; i++) {
        int idx = i * 256 + t;
        int n = idx >> 6, k = idx & 63;
        dst[(size_t)(n0 + n) * dst_ld + k0 + k] = tile[n * 65 + k];
    }
}

// ---------- in-place masked softmax, fp32; also emits bf16 copy ----------
__global__ __launch_bounds__(256)
void softmax_rows_f32(float* __restrict__ S, uint16_t* __restrict__ Sbf,
                      const int* __restrict__ mask, int L)
{
    const int row = blockIdx.x;
    const int b = row >> 11;                 // L == 2048
    float* rp = S + (size_t)row * L;
    uint16_t* bp = Sbf + (size_t)row * L;
    const int* mrow = mask + (size_t)b * L;
    const int t = threadIdx.x;
    const int c0 = t * 8;

    float v[8];
    *(float4*)(v + 0) = *(const float4*)(rp + c0);
    *(float4*)(v + 4) = *(const float4*)(rp + c0 + 4);
    bool mk[8];
    float lmax = -1e30f;
#pragma unroll
    for (int j = 0; j < 8; j++) {
        mk[j] = (mrow[c0 + j] != 0);
        if (mk[j]) lmax = fmaxf(lmax, v[j]);
    }
#pragma unroll
    for (int off = 32; off > 0; off >>= 1)
        lmax = fmaxf(lmax, __shfl_xor(lmax, off, 64));

    __shared__ float redm[4];
    __shared__ float reds[4];
    const int w = t >> 6, lane = t & 63;
    if (lane == 0) redm[w] = lmax;
    __syncthreads();
    lmax = fmaxf(fmaxf(redm[0], redm[1]), fmaxf(redm[2], redm[3]));

    float e[8];
    float lsum = 0.f;
#pragma unroll
    for (int j = 0; j < 8; j++) {
        e[j] = mk[j] ? __expf(v[j] - lmax) : 0.0f;
        lsum += e[j];
    }
#pragma unroll
    for (int off = 32; off > 0; off >>= 1)
        lsum += __shfl_xor(lsum, off, 64);
    if (lane == 0) reds[w] = lsum;
    __syncthreads();
    lsum = reds[0] + reds[1] + reds[2] + reds[3];

    const float inv = 1.0f / lsum;
    uint16_t ub[8];
#pragma unroll
    for (int j = 0; j < 8; j++) {
        v[j] = e[j] * inv;
        ub[j] = f2bf(v[j]);
    }
    *(float4*)(rp + c0)     = *(const float4*)(v + 0);
    *(float4*)(rp + c0 + 4) = *(const float4*)(v + 4);
    *(uint4*)(bp + c0)      = *(const uint4*)ub;
}

extern "C" void kernel_launch(void* const* d_in, const int* in_sizes, int n_in,
                              void* d_out, int out_size, void* d_ws, size_t ws_size,
                              hipStream_t stream)
{
    const float* x    = (const float*)d_in[0];  // [4,2048,1024] fp32
    const int*   mask = (const int*)d_in[1];    // [4,1,2048] int32
    const float* W1   = (const float*)d_in[2];  // [1024,1024]
    const float* b1   = (const float*)d_in[3];  // [1024]
    const float* W2   = (const float*)d_in[4];  // [1024,2048]
    const float* b2   = (const float*)d_in[5];  // [2048]
    const float* D2L  = (const float*)d_in[6];  // [1024,4096]

    const int Lr = 2048, D = 1024, M = 4 * Lr;  // M = 8192
    float* outp = (float*)d_out;                // [8192][1024] fp32
    float* attn = outp + (size_t)M * D;         // [8192][2048] fp32

    // ws layout (bf16 elems): W1T | W2T | D2LT | h(->vT) | kv(->attn_bf16)
    uint16_t* W1T  = (uint16_t*)d_ws;                   // 1024*1024
    uint16_t* W2T  = W1T + 1024 * 1024;                 // 2048*1024
    uint16_t* D2LT = W2T + 2048 * 1024;                 // 2048*1024
    uint16_t* hbuf = D2LT + 2048 * 1024;                // 8192*1024
    uint16_t* kv   = hbuf + (size_t)M * D;              // 8192*2048
    uint16_t* vT   = hbuf;   // reuse h region after GEMM2
    uint16_t* abf  = kv;     // reuse kv region after scores GEMM

    dim3 blk(256);

    // opt-in to 128 KiB dynamic LDS for the 8-phase engine (idempotent, host-side,
    // graph-capture-safe: not a stream/alloc/sync op)
    hipFuncSetAttribute(reinterpret_cast<const void*>(&gemm256_bt<0, 0>),
                        hipFuncAttributeMaxDynamicSharedMemorySize, 131072);
    hipFuncSetAttribute(reinterpret_cast<const void*>(&gemm256_bt<1, 0>),
                        hipFuncAttributeMaxDynamicSharedMemorySize, 131072);

    // weight cast+transpose -> bf16 [N][K]
    transpose_f32_to_bf16<<<dim3(16, 16), blk, 0, stream>>>(W1,  W1T,  1024, 1024);
    transpose_f32_to_bf16<<<dim3(32, 16), blk, 0, stream>>>(W2,  W2T,  2048, 1024);
    transpose_f32_to_bf16<<<dim3(32, 16), blk, 0, stream>>>(D2L, D2LT, 4096, 1024);

    // h = relu(x @ W1 + b1)   [8192,1024] K=1024, A fp32, out bf16 (legacy engine)
    gemm_bt<1, 0, 1><<<dim3(8, 64, 1), blk, 0, stream>>>(x, W1T, b1, hbuf,
        1024, 1024, 1024, 1024, 0, 0, 0);

    // kv = h @ W2 + b2        [8192,2048] K=1024  -> 256^2 8-phase engine
    gemm256_bt<0, 0><<<dim3(8, 32), dim3(512), 131072, stream>>>(hbuf, W2T, b2, kv,
        1024, 1024, 1024, 2048);

    // vT[b] = transpose(kv[b][:,1024:2048]) -> [4][1024][2048] bf16
    transpose_bf16<<<dim3(16, 32, 4), blk, 0, stream>>>(kv + 1024, vT,
        2048, 2048, (long long)2048 * 2048, (long long)1024 * 2048);

    // scores = k @ D_to_L[:, :2048] -> attn fp32, K=1024 -> 256^2 8-phase engine
    gemm256_bt<1, 0><<<dim3(8, 32), dim3(512), 131072, stream>>>(kv, D2LT, nullptr, attn,
        1024, 2048, 1024, 2048);

    // masked softmax in-place (fp32) + bf16 copy into dead kv region
    softmax_rows_f32<<<dim3(8192), blk, 0, stream>>>(attn, abf, mask, Lr);

    // output = attn @ v (batched over 4), A bf16, out fp32, K=2048 (legacy engine)
    gemm_bt<0, 1, 0><<<dim3(8, 16, 4), blk, 0, stream>>>(abf, vT, nullptr, outp,
        2048, 2048, 2048, 1024,
        (long long)2048 * 2048, (long long)1024 * 2048, (long long)2048 * 1024);
}

// Round 2
// 328.423 us; speedup vs baseline: 1.0853x; 1.0662x over previous
//
#include <hip/hip_runtime.h>
#include <cstdint>
#include <cstddef>

// ---------- bf16 helpers (bit-level) ----------
__device__ __forceinline__ uint16_t f2bf(float f) {
    union { float f; uint32_t i; } w; w.f = f;
    uint32_t x = w.i;
    uint32_t r = (x + 0x7FFFu + ((x >> 16) & 1u)) >> 16;   // RNE
    return (uint16_t)r;
}

typedef __bf16 bf16x8 __attribute__((ext_vector_type(8)));
typedef float  f32x4  __attribute__((ext_vector_type(4)));

// async global->LDS, 16B per lane; LDS dest is wave-uniform base + lane*16
__device__ __forceinline__ void load_lds16(const void* gptr, void* lptr) {
    __builtin_amdgcn_global_load_lds(
        (__attribute__((address_space(1))) void*)gptr,
        (__attribute__((address_space(3))) void*)lptr,
        16, 0, 0);
}

// ---------- 256xBN 8-phase GEMM engine (T1+T2+T3+T4+T5, plain HIP) ----------
// C[M,N] = act(A[M,K] @ BT[N,K]^T + bias); A,BT bf16; BK=64 as 2 kh-subtiles.
// BN=256: 8 waves as 2Mx4N, per-wave 128x64, acc[8][4], 4 phases/K-tile,
//         B staged with 2 gload_lds per kh, counted vmcnt(4).
// BN=128: 8 waves as 4Mx2N, per-wave  64x64, acc[4][4], 2 phases/K-tile,
//         B staged with 1 gload_lds per kh, counted vmcnt(3).
// LDS: A = 2buf x 2kh x [256][32] @ 0 (64KB); B = 2buf x 2kh x [BN][32] @ 64KB.
// Chunk swizzle (T2): LDS slot (r,q) holds global 16B chunk (q ^ ((r>>1)&3)) of
// row r -> ds_read_b128 frag reads are <=2-way bank aliased (free, m136);
// gload_lds dest stays linear (m104), source address carries the same XOR.
// Phase (m201-faithful): [ds_read frags][issue gload_lds][s_barrier]
//   [s_waitcnt lgkmcnt(0)][setprio(1) 16 MFMA setprio(0)][counted vmcnt][s_barrier]
// The loop never drains vmcnt to 0 (T4): 1 K-tile of loads stays in flight.
// Batch: B-operand only; bz = by >> byShift (A and C rows are batch-contiguous).
template<int BN, int OUTFP32, int RELU>
__global__ __launch_bounds__(512, 2)
void gemm256(const uint16_t* __restrict__ A, const uint16_t* __restrict__ BT,
             const float* __restrict__ bias, void* __restrict__ Cv,
             int K, int lda, int ldb, int ldc,
             long long sB, int byShift)
{
    extern __shared__ uint16_t lds[];
    constexpr int SB  = (BN == 256) ? 2 : 1;  // B gload_lds insts per kh
    constexpr int WN  = BN / 64;              // waves along N (4 or 2)
    constexpr int MI  = 2 * WN;               // frag-rows per wave (8 or 4)
    constexpr int SBE = BN * 32;              // B subtile elems

    // XCD swizzle: 256 blocks, xcd = g&7 (round-robin dispatch); each XCD owns
    // 4 contiguous M-tiles; consecutive ii share the same bx (B-panel L2 reuse).
    const int g   = (int)blockIdx.x + (int)gridDim.x * (int)blockIdx.y;
    const int xcd = g & 7, ii = g >> 3;
    const int by  = xcd * 4 + (ii & 3);
    const int bx  = ii >> 2;
    const int gm0 = by * 256, gn0 = bx * BN;
    const int bz  = by >> byShift;
    BT += (long long)bz * sB;

    const int t    = threadIdx.x;
    const int w    = t >> 6, lane = t & 63;
    const int l15  = lane & 15, quad = lane >> 4;
    const int wr   = w / WN, wc = w % WN;

    // frag-read swizzle + row bases
    const int cpr  = quad ^ ((l15 >> 1) & 3);
    const int arow = wr * (32 * WN) + l15;    // + (mh*64) + i*16
    const int brow = wc * 64 + l15;           // + ni*16

    // staging map: thread t covers row r0 = t>>2 (0..127), 16B chunk qg of that
    // row, where qg = (t&3) ^ ((r0>>1)&3) (r0>>1 == t>>3).
    const int r0 = t >> 2;
    const int qg = (t & 3) ^ ((t >> 3) & 3);
    const uint16_t* aS0 = A  + (size_t)(gm0 + r0) * lda + qg * 8;
    const uint16_t* aS1 = aS0 + (size_t)128 * lda;
    const uint16_t* bS0 = BT + (size_t)(gn0 + r0) * ldb + qg * 8;
    const uint16_t* bS1 = bS0 + (size_t)128 * ldb;   // deref'd only if BN==256
    const int ldw = w * 512;                  // per-wave LDS elem offset

#define SUBA(nb, kh) (lds + ((nb) * 2 + (kh)) * 8192)
#define SUBB(nb, kh) (lds + 32768 + ((nb) * 2 + (kh)) * SBE)
#define STAGE_A(nb, kh, k0s) do {                                               \
        load_lds16(aS0 + (k0s) + (kh) * 32, (void*)(SUBA(nb, kh) + ldw));       \
        load_lds16(aS1 + (k0s) + (kh) * 32, (void*)(SUBA(nb, kh) + 4096 + ldw));\
    } while (0)
#define STAGE_B(nb, kh, k0s) do {                                               \
        load_lds16(bS0 + (k0s) + (kh) * 32, (void*)(SUBB(nb, kh) + ldw));       \
        if constexpr (BN == 256)                                                \
            load_lds16(bS1 + (k0s) + (kh) * 32,                                 \
                       (void*)(SUBB(nb, kh) + 4096 + ldw));                     \
    } while (0)
#define VMW do {                                                                \
        if constexpr (SB == 2) asm volatile("s_waitcnt vmcnt(4)" ::: "memory"); \
        else                   asm volatile("s_waitcnt vmcnt(3)" ::: "memory"); \
    } while (0)
#define LGKM0 asm volatile("s_waitcnt lgkmcnt(0)" ::: "memory")
#define NOWAIT ((void)0)

    f32x4 acc[MI][4] = {};
    bf16x8 bF[4];

    // prologue: stage tile 0 fully; wait until (Ak0,Bk0) landed
    STAGE_A(0, 0, 0); STAGE_B(0, 0, 0); STAGE_A(0, 1, 0); STAGE_B(0, 1, 0);
    VMW;
    __builtin_amdgcn_s_barrier();

    const int NT = K >> 6;
    for (int kt = 0; kt < NT; ++kt) {
        const int buf = kt & 1, nb = buf ^ 1;
        const int nk0 = (kt + 1 < NT) ? ((kt + 1) << 6) : 0;   // wrap: dead stage

        if constexpr (BN == 256) {
            // 4 phases: (kh, mh); bF persists across the mh pair.
#define PHASE256(kh, mh, STAGE_STMT, VM_STMT)                                       \
            {                                                                       \
                const uint16_t* As_ = SUBA(buf, kh);                                \
                const uint16_t* Bs_ = SUBB(buf, kh);                                \
                bf16x8 aF[4];                                                       \
                _Pragma("unroll")                                                   \
                for (int i = 0; i < 4; i++)                                         \
                    aF[i] = *(const bf16x8*)(As_ + (arow + (mh) * 64 + i * 16) * 32 + cpr * 8); \
                if ((mh) == 0) {                                                    \
                    _Pragma("unroll")                                               \
                    for (int ni = 0; ni < 4; ni++)                                  \
                        bF[ni] = *(const bf16x8*)(Bs_ + (brow + ni * 16) * 32 + cpr * 8); \
                }                                                                   \
                STAGE_STMT;                                                         \
                __builtin_amdgcn_s_barrier();                                       \
                LGKM0;                                                              \
                __builtin_amdgcn_s_setprio(1);                                      \
                _Pragma("unroll")                                                   \
                for (int i = 0; i < 4; i++)                                         \
                    _Pragma("unroll")                                               \
                    for (int ni = 0; ni < 4; ni++)                                  \
                        acc[(mh) * 4 + i][ni] = __builtin_amdgcn_mfma_f32_16x16x32_bf16( \
                            aF[i], bF[ni], acc[(mh) * 4 + i][ni], 0, 0, 0);         \
                __builtin_amdgcn_s_setprio(0);                                      \
                VM_STMT;                                                            \
                __builtin_amdgcn_s_barrier();                                       \
            }
            PHASE256(0, 0, STAGE_A(nb, 0, nk0), NOWAIT)
            PHASE256(0, 1, STAGE_B(nb, 0, nk0), VMW)
            PHASE256(1, 0, STAGE_A(nb, 1, nk0), NOWAIT)
            PHASE256(1, 1, STAGE_B(nb, 1, nk0), VMW)
#undef PHASE256
        } else {
            // 2 phases: (kh); 16 MFMA per phase (all 4 mi x 4 ni).
#define PHASE128(kh)                                                                \
            {                                                                       \
                const uint16_t* As_ = SUBA(buf, kh);                                \
                const uint16_t* Bs_ = SUBB(buf, kh);                                \
                bf16x8 aF[4], bG[4];                                                \
                _Pragma("unroll")                                                   \
                for (int i = 0; i < 4; i++)                                         \
                    aF[i] = *(const bf16x8*)(As_ + (arow + i * 16) * 32 + cpr * 8); \
                _Pragma("unroll")                                                   \
                for (int ni = 0; ni < 4; ni++)                                      \
                    bG[ni] = *(const bf16x8*)(Bs_ + (brow + ni * 16) * 32 + cpr * 8); \
                STAGE_A(nb, kh, nk0);                                               \
                STAGE_B(nb, kh, nk0);                                               \
                __builtin_amdgcn_s_barrier();                                       \
                LGKM0;                                                              \
                __builtin_amdgcn_s_setprio(1);                                      \
                _Pragma("unroll")                                                   \
                for (int i = 0; i < 4; i++)                                         \
                    _Pragma("unroll")                                               \
                    for (int ni = 0; ni < 4; ni++)                                  \
                        acc[i][ni] = __builtin_amdgcn_mfma_f32_16x16x32_bf16(       \
                            aF[i], bG[ni], acc[i][ni], 0, 0, 0);                    \
                __builtin_amdgcn_s_setprio(0);                                      \
                VMW;                                                                \
                __builtin_amdgcn_s_barrier();                                       \
            }
            PHASE128(0)
            PHASE128(1)
#undef PHASE128
        }
    }
    asm volatile("s_waitcnt vmcnt(0)" ::: "memory");   // drain dead stage

    // epilogue: C/D layout col=lane&15, row=quad*4+reg
#pragma unroll
    for (int ni = 0; ni < 4; ni++) {
        const int gcol = gn0 + wc * 64 + ni * 16 + l15;
        const float bv = bias ? bias[gcol] : 0.0f;
#pragma unroll
        for (int mi = 0; mi < MI; mi++) {
#pragma unroll
            for (int r = 0; r < 4; r++) {
                const int grow = gm0 + wr * (32 * WN) + mi * 16 + quad * 4 + r;
                float v = acc[mi][ni][r] + bv;
                if (RELU) v = fmaxf(v, 0.0f);
                if (OUTFP32) ((float*)Cv)[(size_t)grow * ldc + gcol] = v;
                else         ((uint16_t*)Cv)[(size_t)grow * ldc + gcol] = f2bf(v);
            }
        }
    }
#undef SUBA
#undef SUBB
#undef STAGE_A
#undef STAGE_B
#undef VMW
#undef LGKM0
#undef NOWAIT
}

// ---------- elementwise cast fp32 -> bf16 (8 elems/thread) ----------
__global__ __launch_bounds__(256)
void cast_f32_bf16(const float* __restrict__ src, uint16_t* __restrict__ dst)
{
    const size_t i = ((size_t)blockIdx.x * 256 + threadIdx.x) * 8;
    float4 a = *(const float4*)(src + i);
    float4 b = *(const float4*)(src + i + 4);
    union { __bf16 h[8]; uint4 q; } u;
    u.h[0] = (__bf16)a.x; u.h[1] = (__bf16)a.y;
    u.h[2] = (__bf16)a.z; u.h[3] = (__bf16)a.w;
    u.h[4] = (__bf16)b.x; u.h[5] = (__bf16)b.y;
    u.h[6] = (__bf16)b.z; u.h[7] = (__bf16)b.w;
    *(uint4*)(dst + i) = u.q;
}

// ---------- transpose fp32 -> bf16: dst[n][k] = bf16(src[k][n]) ----------
__global__ __launch_bounds__(256)
void transpose_f32_to_bf16(const float* __restrict__ src, uint16_t* __restrict__ dst,
                           int src_ld, int dst_ld)
{
    __shared__ uint16_t tile[64 * 65];
    const int k0 = blockIdx.y * 64, n0 = blockIdx.x * 64;
    const int t = threadIdx.x;
#pragma unroll
    for (int i = 0; i < 16; i++) {
        int idx = i * 256 + t;
        int r = idx >> 6, c = idx & 63;
        tile[c * 65 + r] = f2bf(src[(size_t)(k0 + r) * src_ld + n0 + c]);
    }
    __syncthreads();
#pragma unroll
    for (int i = 0; i < 16; i++) {
        int idx = i * 256 + t;
        int n = idx >> 6, k = idx & 63;
        dst[(size_t)(n0 + n) * dst_ld + k0 + k] = tile[n * 65 + k];
    }
}

// ---------- transpose bf16 -> bf16 (batched) ----------
__global__ __launch_bounds__(256)
void transpose_bf16(const uint16_t* __restrict__ src, uint16_t* __restrict__ dst,
                    int src_ld, int dst_ld, long long sS, long long sD)
{
    __shared__ uint16_t tile[64 * 65];
    src += (long long)blockIdx.z * sS;
    dst += (long long)blockIdx.z * sD;
    const int k0 = blockIdx.y * 64, n0 = blockIdx.x * 64;
    const int t = threadIdx.x;
#pragma unroll
    for (int i = 0; i < 16; i++) {
        int idx = i * 256 + t;
        int r = idx >> 6, c = idx & 63;
        tile[c * 65 + r] = src[(size_t)(k0 + r) * src_ld + n0 + c];
    }
    __syncthreads();
#pragma unroll
    for (int i = 0; i < 16; i++) {
        int idx = i * 256 + t;
        int n = idx >> 6, k = idx & 63;
        dst[(size_t)(n0 + n) * dst_ld + k0 + k] = tile[n * 65 + k];
    }
}

// ---------- in-place masked softmax, fp32; also emits bf16 copy ----------
__global__ __launch_bounds__(256)
void softmax_rows_f32(float* __restrict__ S, uint16_t* __restrict__ Sbf,
                      const int* __restrict__ mask, int L)
{
    const int row = blockIdx.x;
    const int b = row >> 11;                 // L == 2048
    float* rp = S + (size_t)row * L;
    uint16_t* bp = Sbf + (size_t)row * L;
    const int* mrow = mask + (size_t)b * L;
    const int t = threadIdx.x;
    const int c0 = t * 8;

    float v[8];
    *(float4*)(v + 0) = *(const float4*)(rp + c0);
    *(float4*)(v + 4) = *(const float4*)(rp + c0 + 4);
    bool mk[8];
    float lmax = -1e30f;
#pragma unroll
    for (int j = 0; j < 8; j++) {
        mk[j] = (mrow[c0 + j] != 0);
        if (mk[j]) lmax = fmaxf(lmax, v[j]);
    }
#pragma unroll
    for (int off = 32; off > 0; off >>= 1)
        lmax = fmaxf(lmax, __shfl_xor(lmax, off, 64));

    __shared__ float redm[4];
    __shared__ float reds[4];
    const int w = t >> 6, lane = t & 63;
    if (lane == 0) redm[w] = lmax;
    __syncthreads();
    lmax = fmaxf(fmaxf(redm[0], redm[1]), fmaxf(redm[2], redm[3]));

    float e[8];
    float lsum = 0.f;
#pragma unroll
    for (int j = 0; j < 8; j++) {
        e[j] = mk[j] ? __expf(v[j] - lmax) : 0.0f;
        lsum += e[j];
    }
#pragma unroll
    for (int off = 32; off > 0; off >>= 1)
        lsum += __shfl_xor(lsum, off, 64);
    if (lane == 0) reds[w] = lsum;
    __syncthreads();
    lsum = reds[0] + reds[1] + reds[2] + reds[3];

    const float inv = 1.0f / lsum;
    uint16_t ub[8];
#pragma unroll
    for (int j = 0; j < 8; j++) {
        v[j] = e[j] * inv;
        ub[j] = f2bf(v[j]);
    }
    *(float4*)(rp + c0)     = *(const float4*)(v + 0);
    *(float4*)(rp + c0 + 4) = *(const float4*)(v + 4);
    *(uint4*)(bp + c0)      = *(const uint4*)ub;
}

extern "C" void kernel_launch(void* const* d_in, const int* in_sizes, int n_in,
                              void* d_out, int out_size, void* d_ws, size_t ws_size,
                              hipStream_t stream)
{
    const float* x    = (const float*)d_in[0];  // [4,2048,1024] fp32
    const int*   mask = (const int*)d_in[1];    // [4,1,2048] int32
    const float* W1   = (const float*)d_in[2];  // [1024,1024]
    const float* b1   = (const float*)d_in[3];  // [1024]
    const float* W2   = (const float*)d_in[4];  // [1024,2048]
    const float* b2   = (const float*)d_in[5];  // [2048]
    const float* D2L  = (const float*)d_in[6];  // [1024,4096]

    const int Lr = 2048, D = 1024, M = 4 * Lr;  // M = 8192
    float* outp = (float*)d_out;                // [8192][1024] fp32
    float* attn = outp + (size_t)M * D;         // [8192][2048] fp32

    // ws layout (bf16 elems): W1T | W2T | D2LT | h(->vT) | kv(->attn_bf16) | xbf
    uint16_t* W1T  = (uint16_t*)d_ws;                   // 1024*1024
    uint16_t* W2T  = W1T + 1024 * 1024;                 // 2048*1024
    uint16_t* D2LT = W2T + 2048 * 1024;                 // 2048*1024
    uint16_t* hbuf = D2LT + 2048 * 1024;                // 8192*1024
    uint16_t* kv   = hbuf + (size_t)M * D;              // 8192*2048
    uint16_t* xbf  = kv + (size_t)M * 2048;             // 8192*1024
    uint16_t* vT   = hbuf;   // reuse h region after kv GEMM
    uint16_t* abf  = kv;     // reuse kv region after scores GEMM

    dim3 blk(256);
    const dim3 g256(8, 32), b512(512);

    // opt-in to the dynamic LDS sizes (host-side attr set; graph-capture-safe)
    hipFuncSetAttribute(reinterpret_cast<const void*>(&gemm256<256, 0, 0>),
                        hipFuncAttributeMaxDynamicSharedMemorySize, 131072);
    hipFuncSetAttribute(reinterpret_cast<const void*>(&gemm256<256, 1, 0>),
                        hipFuncAttributeMaxDynamicSharedMemorySize, 131072);
    hipFuncSetAttribute(reinterpret_cast<const void*>(&gemm256<128, 0, 1>),
                        hipFuncAttributeMaxDynamicSharedMemorySize, 98304);
    hipFuncSetAttribute(reinterpret_cast<const void*>(&gemm256<128, 1, 0>),
                        hipFuncAttributeMaxDynamicSharedMemorySize, 98304);

    // x -> bf16 (8192*1024 elems, 8/thread)
    cast_f32_bf16<<<dim3(4096), blk, 0, stream>>>(x, xbf);

    // weight cast+transpose -> bf16 [N][K]
    transpose_f32_to_bf16<<<dim3(16, 16), blk, 0, stream>>>(W1,  W1T,  1024, 1024);
    transpose_f32_to_bf16<<<dim3(32, 16), blk, 0, stream>>>(W2,  W2T,  2048, 1024);
    transpose_f32_to_bf16<<<dim3(32, 16), blk, 0, stream>>>(D2L, D2LT, 4096, 1024);

    // h = relu(x @ W1 + b1)   [8192,1024] K=1024  (BN=128 engine)
    gemm256<128, 0, 1><<<g256, b512, 98304, stream>>>(xbf, W1T, b1, hbuf,
        1024, 1024, 1024, 1024, 0, 30);

    // kv = h @ W2 + b2        [8192,2048] K=1024  (BN=256 engine)
    gemm256<256, 0, 0><<<g256, b512, 131072, stream>>>(hbuf, W2T, b2, kv,
        1024, 1024, 1024, 2048, 0, 30);

    // vT[b] = transpose(kv[b][:,1024:2048]) -> [4][1024][2048] bf16
    transpose_bf16<<<dim3(16, 32, 4), blk, 0, stream>>>(kv + 1024, vT,
        2048, 2048, (long long)2048 * 2048, (long long)1024 * 2048);

    // scores = k @ D_to_L[:, :2048] -> attn fp32, K=1024  (BN=256 engine)
    gemm256<256, 1, 0><<<g256, b512, 131072, stream>>>(kv, D2LT, nullptr, attn,
        1024, 2048, 1024, 2048, 0, 30);

    // masked softmax in-place (fp32) + bf16 copy into dead kv region
    softmax_rows_f32<<<dim3(8192), blk, 0, stream>>>(attn, abf, mask, Lr);

    // output = attn @ v, batched over 4 via B-pointer (A,C rows batch-contiguous)
    // [8192,1024] K=2048  (BN=128 engine)
    gemm256<128, 1, 0><<<g256, b512, 98304, stream>>>(abf, vT, nullptr, outp,
        2048, 2048, 2048, 1024, (long long)1024 * 2048, 3);
}